// Round 5
// baseline (9768.208 us; speedup 1.0000x reference)
//
#include <hip/hip_runtime.h>

// Problem constants
#define HW     16384      // 128*128
#define NB     8
#define CDIM   192
#define CH3    576
#define NHEADS 4
#define CHH    48
#define TROWS  32         // FFN tile rows
#define TSLOT  34         // f1/f2 row slots (TROWS + 2 halo)
#define NT     (TSLOT*128)  // 4352
#define NF     (TROWS*128)  // 4096

__device__ __forceinline__ float gelu_f(float x) {
    return 0.5f * x * (1.0f + erff(x * 0.70710678118654752f));
}

// ---------------------------------------------------------------------------
// LayerNorm stats per pixel over 192 channels, one batch. grid 64 x 256
// ---------------------------------------------------------------------------
__global__ __launch_bounds__(256) void ln_stats1(const float* __restrict__ x,
                                                 float* __restrict__ mu,
                                                 float* __restrict__ rstd) {
    int p = blockIdx.x * 256 + threadIdx.x;
    float s = 0.f, ss = 0.f;
    for (int c = 0; c < CDIM; ++c) {
        float v = x[(size_t)c * HW + p];
        s += v; ss += v * v;
    }
    float m = s * (1.0f / CDIM);
    float var = ss * (1.0f / CDIM) - m * m;
    mu[p] = m;
    rstd[p] = 1.0f / sqrtf(var + 1e-5f);
}

// ---------------------------------------------------------------------------
// Single-batch tiled GEMM: out[m, n] = sum_k A[m,k] * B[k,n]  (+epilogues)
// Block tile 64(M) x 256(N), K-chunks of 16, 256 thr, 8x8 micro-tile.
// B_MODE 0: B = layernorm(Bin) on the fly;  1: plain fp32 buffer
// EPI 0: +bias; 1: +bias,gelu; 2: +bias,+res
// Channel strides b_cs / r_cs / o_cs passed per tensor.
// ---------------------------------------------------------------------------
template <int B_MODE, int EPI>
__global__ __launch_bounds__(256) void gemm1(
    const float* __restrict__ Aw,
    const float* __restrict__ Bin, int b_cs,
    const float* __restrict__ mu, const float* __restrict__ rstd,
    const float* __restrict__ lnw, const float* __restrict__ lnb,
    const float* __restrict__ bias,
    const float* __restrict__ res, int r_cs,
    float* __restrict__ outf, int o_cs,
    int M, int K) {
    __shared__ float As[16][68];
    __shared__ float Bs[16][256];
    const int n0 = blockIdx.x * 256;
    const int m0 = blockIdx.y * 64;
    const int tid = threadIdx.x;
    const int tm8 = (tid >> 5) << 3;
    const int tn8 = (tid & 31) << 3;
    const int am  = tid >> 2;            // 0..63
    const int ak4 = (tid & 3) << 2;      // 0,4,8,12
    const int bk   = tid >> 4;           // 0..15
    const int bn16 = (tid & 15) << 4;    // 0..240

    float acc[8][8];
#pragma unroll
    for (int i = 0; i < 8; ++i)
#pragma unroll
        for (int j = 0; j < 8; ++j) acc[i][j] = 0.f;

    for (int k0 = 0; k0 < K; k0 += 16) {
        if (k0) __syncthreads();
        float4 a4 = *(const float4*)(Aw + (size_t)(m0 + am) * K + k0 + ak4);
        As[ak4 + 0][am] = a4.x; As[ak4 + 1][am] = a4.y;
        As[ak4 + 2][am] = a4.z; As[ak4 + 3][am] = a4.w;
        const float* xp = Bin + (size_t)(k0 + bk) * b_cs + n0 + bn16;
        if (B_MODE == 1) {
#pragma unroll
            for (int q = 0; q < 4; ++q) {
                float4 xv = *(const float4*)(xp + 4 * q);
                Bs[bk][bn16 + 4 * q + 0] = xv.x;
                Bs[bk][bn16 + 4 * q + 1] = xv.y;
                Bs[bk][bn16 + 4 * q + 2] = xv.z;
                Bs[bk][bn16 + 4 * q + 3] = xv.w;
            }
        } else {
            const float* mp = mu + n0 + bn16;
            const float* rp = rstd + n0 + bn16;
            float lw = lnw[k0 + bk], lb = lnb[k0 + bk];
#pragma unroll
            for (int q = 0; q < 4; ++q) {
                float4 xv = *(const float4*)(xp + 4 * q);
                float4 mv = *(const float4*)(mp + 4 * q);
                float4 rv = *(const float4*)(rp + 4 * q);
                Bs[bk][bn16 + 4 * q + 0] = (xv.x - mv.x) * rv.x * lw + lb;
                Bs[bk][bn16 + 4 * q + 1] = (xv.y - mv.y) * rv.y * lw + lb;
                Bs[bk][bn16 + 4 * q + 2] = (xv.z - mv.z) * rv.z * lw + lb;
                Bs[bk][bn16 + 4 * q + 3] = (xv.w - mv.w) * rv.w * lw + lb;
            }
        }
        __syncthreads();
#pragma unroll
        for (int kk = 0; kk < 16; ++kk) {
            float av[8], bv[8];
            *(float4*)&av[0] = *(const float4*)&As[kk][tm8];
            *(float4*)&av[4] = *(const float4*)&As[kk][tm8 + 4];
            *(float4*)&bv[0] = *(const float4*)&Bs[kk][tn8];
            *(float4*)&bv[4] = *(const float4*)&Bs[kk][tn8 + 4];
#pragma unroll
            for (int i = 0; i < 8; ++i)
#pragma unroll
                for (int j = 0; j < 8; ++j)
                    acc[i][j] = fmaf(av[i], bv[j], acc[i][j]);
        }
    }

#pragma unroll
    for (int i = 0; i < 8; ++i) {
        int m = m0 + tm8 + i;
        float bs = bias[m];
        float v[8];
#pragma unroll
        for (int j = 0; j < 8; ++j) v[j] = acc[i][j] + bs;
        if (EPI == 1) {
#pragma unroll
            for (int j = 0; j < 8; ++j) v[j] = gelu_f(v[j]);
        }
        float4 o0, o1;
        if (EPI == 2) {
            size_t rb = (size_t)m * r_cs + n0 + tn8;
            float4 r0 = *(const float4*)(res + rb);
            float4 r1 = *(const float4*)(res + rb + 4);
            o0.x = v[0] + r0.x; o0.y = v[1] + r0.y; o0.z = v[2] + r0.z; o0.w = v[3] + r0.w;
            o1.x = v[4] + r1.x; o1.y = v[5] + r1.y; o1.z = v[6] + r1.z; o1.w = v[7] + r1.w;
        } else {
            o0.x = v[0]; o0.y = v[1]; o0.z = v[2]; o0.w = v[3];
            o1.x = v[4]; o1.y = v[5]; o1.z = v[6]; o1.w = v[7];
        }
        size_t ob = (size_t)m * o_cs + n0 + tn8;
        *(float4*)(outf + ob) = o0;
        *(float4*)(outf + ob + 4) = o1;
    }
}

// ---------------------------------------------------------------------------
// Depthwise 3x3 (pad=1) + bias + prompt on a 192-channel full image.
// Caller pre-offsets w9/b1 by the channel group. grid (64, 192)
// ---------------------------------------------------------------------------
__global__ __launch_bounds__(256) void dwp(const float* __restrict__ in,
                                           const float* __restrict__ w9,
                                           const float* __restrict__ b1,
                                           const float* __restrict__ prompt,
                                           float* __restrict__ out) {
    int p = blockIdx.x * 256 + threadIdx.x;
    int c = blockIdx.y;
    int h = p >> 7, w = p & 127;
    const float* ip = in + (size_t)c * HW;
    const float* wp = w9 + c * 9;
    float acc = b1[c] + prompt[c];
#pragma unroll
    for (int ky = 0; ky < 3; ++ky) {
        int hy = h + ky - 1;
        if ((unsigned)hy < 128u) {
            int rb = hy << 7;
#pragma unroll
            for (int kx = 0; kx < 3; ++kx) {
                int wx = w + kx - 1;
                if ((unsigned)wx < 128u)
                    acc += wp[ky * 3 + kx] * ip[rb + wx];
            }
        }
    }
    out[(size_t)c * HW + p] = acc;
}

// ---------------------------------------------------------------------------
// 1/max(L2norm,1e-12) per channel (384 q,k channels). grid 384 x 256
// ---------------------------------------------------------------------------
__global__ __launch_bounds__(256) void inv_norms1(const float* __restrict__ qk,
                                                  float* __restrict__ invn) {
    int ch = blockIdx.x;
    const float* p = qk + (size_t)ch * HW;
    float ss = 0.f;
    for (int i = threadIdx.x; i < HW; i += 256) { float v = p[i]; ss += v * v; }
    __shared__ float r[256];
    r[threadIdx.x] = ss;
    __syncthreads();
    for (int off = 128; off; off >>= 1) {
        if (threadIdx.x < (unsigned)off) r[threadIdx.x] += r[threadIdx.x + off];
        __syncthreads();
    }
    if (threadIdx.x == 0) invn[ch] = 1.0f / fmaxf(sqrtf(r[0]), 1e-12f);
}

// ---------------------------------------------------------------------------
// Gram partials of q~,k~ (384-ch buffer: q at ch 0.., k at ch 192..).
// grid (16 slices, 4 heads); slot = h*64 + sl*4 + ns.
// ---------------------------------------------------------------------------
__global__ __launch_bounds__(256) void gram1(const float* __restrict__ qk,
                                             float* __restrict__ G0p) {
    int sl = blockIdx.x, h = blockIdx.y;
    const int tid = threadIdx.x;
    const int ns = tid >> 6;
    const int lane = tid & 63;
    const int ci = lane >> 3;
    const int di = lane & 7;

    __shared__ float qs[48][68];
    __shared__ float ks[48][68];

    float acc[6][6];
#pragma unroll
    for (int i = 0; i < 6; ++i)
#pragma unroll
        for (int j = 0; j < 6; ++j) acc[i][j] = 0.f;

    const size_t qbase = (size_t)(h * CHH) * HW;
    const size_t kbase = (size_t)(192 + h * CHH) * HW;
    const int nstart = sl << 10;

    for (int t = 0; t < 1024; t += 64) {
        __syncthreads();
        for (int sidx = tid; sidx < 768; sidx += 256) {
            int which = sidx >= 384;
            int r  = (sidx & 383) >> 3;
            int c8 = (sidx & 7) << 3;
            size_t src = (which ? kbase : qbase) + (size_t)r * HW + nstart + t + c8;
            float4 u0 = *(const float4*)(qk + src);
            float4 u1 = *(const float4*)(qk + src + 4);
            float* dst = which ? &ks[r][c8] : &qs[r][c8];
            dst[0] = u0.x; dst[1] = u0.y; dst[2] = u0.z; dst[3] = u0.w;
            dst[4] = u1.x; dst[5] = u1.y; dst[6] = u1.z; dst[7] = u1.w;
        }
        __syncthreads();
#pragma unroll
        for (int q4 = 0; q4 < 4; ++q4) {
            int n = (ns << 4) + (q4 << 2);
            float4 qv[6], kv[6];
#pragma unroll
            for (int i = 0; i < 6; ++i) qv[i] = *(const float4*)&qs[ci * 6 + i][n];
#pragma unroll
            for (int j = 0; j < 6; ++j) kv[j] = *(const float4*)&ks[di * 6 + j][n];
#pragma unroll
            for (int i = 0; i < 6; ++i)
#pragma unroll
                for (int j = 0; j < 6; ++j) {
                    acc[i][j] = fmaf(qv[i].x, kv[j].x, acc[i][j]);
                    acc[i][j] = fmaf(qv[i].y, kv[j].y, acc[i][j]);
                    acc[i][j] = fmaf(qv[i].z, kv[j].z, acc[i][j]);
                    acc[i][j] = fmaf(qv[i].w, kv[j].w, acc[i][j]);
                }
        }
    }
    float* gp = G0p + (size_t)(h * 64 + sl * 4 + ns) * 2304;
#pragma unroll
    for (int i = 0; i < 6; ++i)
#pragma unroll
        for (int j = 0; j < 6; ++j)
            gp[(ci * 6 + i) * 48 + di * 6 + j] = acc[i][j];
}

// ---------------------------------------------------------------------------
// logits = T * G * invq[c] * invk[d]; softmax over d. grid 4 x 64 thr
// ---------------------------------------------------------------------------
__global__ __launch_bounds__(64) void softmax1(const float* __restrict__ G0p,
                                               const float* __restrict__ invn,
                                               const float* __restrict__ temp,
                                               float* __restrict__ Amat) {
    int h = blockIdx.x;
    int c = threadIdx.x;
    __shared__ float invk_s[48];
    if (c < 48) invk_s[c] = invn[192 + h * CHH + c];
    __syncthreads();
    if (c >= 48) return;
    float T = temp[h];
    float invq = invn[h * CHH + c];
    const float* gp = G0p + (size_t)h * 64 * 2304 + c * 48;
    float lg[48];
    float mx = -1e30f;
    for (int d = 0; d < 48; ++d) {
        float g = 0.f;
        for (int s = 0; s < 64; ++s) g += gp[s * 2304 + d];
        float l = T * g * invq * invk_s[d];
        lg[d] = l;
        mx = fmaxf(mx, l);
    }
    float sum = 0.f;
    for (int d = 0; d < 48; ++d) { float e = expf(lg[d] - mx); lg[d] = e; sum += e; }
    float inv = 1.0f / sum;
    float* ap = Amat + (size_t)h * 2304 + c * 48;
    for (int d = 0; d < 48; ++d) ap[d] = lg[d] * inv;
}

// ---------------------------------------------------------------------------
// attnout[c,n] = sum_d A[c,d] * v~[d,n] per head. grid (64, 4)
// ---------------------------------------------------------------------------
__global__ __launch_bounds__(256) void apply1(const float* __restrict__ vbuf,
                                              const float* __restrict__ Amat,
                                              float* __restrict__ outA) {
    int n = blockIdx.x * 256 + threadIdx.x;
    int h = blockIdx.y;
    __shared__ float As[2304];
    for (int i = threadIdx.x; i < 2304; i += 256) As[i] = Amat[(size_t)h * 2304 + i];
    __syncthreads();
    const float* vp = vbuf + (size_t)(h * CHH) * HW + n;
    float acc[48];
#pragma unroll
    for (int c = 0; c < 48; ++c) acc[c] = 0.f;
    for (int d = 0; d < 48; ++d) {
        float v = vp[(size_t)d * HW];
#pragma unroll
        for (int c = 0; c < 48; ++c) acc[c] = fmaf(As[c * 48 + d], v, acc[c]);
    }
    float* op = outA + (size_t)(h * CHH) * HW + n;
#pragma unroll
    for (int c = 0; c < 48; ++c) op[(size_t)c * HW] = acc[c];
}

// ---------------------------------------------------------------------------
// FFN grouped 3x3 conv (192->576) with LN fused, one row-tile (+halo slots).
// grid (17, 576); slot s in 0..33, global row gr = r0-1+s (may be invalid:
// output for invalid gr is finite junk, never consumed downstream).
// ---------------------------------------------------------------------------
__global__ __launch_bounds__(256) void dwln_tile(const float* __restrict__ x2,
                                                 const float* __restrict__ mu,
                                                 const float* __restrict__ rstd,
                                                 const float* __restrict__ lnw,
                                                 const float* __restrict__ lnb,
                                                 const float* __restrict__ w9,
                                                 const float* __restrict__ b1,
                                                 float* __restrict__ f1, int r0) {
    int p = blockIdx.x * 256 + threadIdx.x;   // 0..4351
    int c = blockIdx.y;
    int s = p >> 7, w = p & 127;
    int gr = r0 - 1 + s;
    int g = c / 3;
    const float* ip = x2 + (size_t)g * HW;
    float lw = lnw[g], lb = lnb[g];
    const float* wp = w9 + c * 9;
    float acc = b1[c];
#pragma unroll
    for (int ky = 0; ky < 3; ++ky) {
        int hy = gr + ky - 1;
        if ((unsigned)hy < 128u) {
            int rb = hy << 7;
#pragma unroll
            for (int kx = 0; kx < 3; ++kx) {
                int wx = w + kx - 1;
                if ((unsigned)wx < 128u) {
                    int idx = rb + wx;
                    float v = (ip[idx] - mu[idx]) * rstd[idx] * lw + lb;
                    acc += wp[ky * 3 + kx] * v;
                }
            }
        }
    }
    f1[(size_t)c * NT + p] = acc;
}

// ---------------------------------------------------------------------------
// FFN depthwise 3x3 on f2 tile -> f3 (TROWS rows). grid (16, 576)
// Bounds-checked on GLOBAL rows so halo junk is never read.
// ---------------------------------------------------------------------------
__global__ __launch_bounds__(256) void dw2_tile(const float* __restrict__ f2,
                                                const float* __restrict__ w9,
                                                const float* __restrict__ b1,
                                                float* __restrict__ f3, int r0) {
    int p = blockIdx.x * 256 + threadIdx.x;   // 0..4095
    int c = blockIdx.y;
    int rr = p >> 7, w = p & 127;
    const float* ip = f2 + (size_t)c * NT;
    const float* wp = w9 + c * 9;
    float acc = b1[c];
#pragma unroll
    for (int ky = 0; ky < 3; ++ky) {
        int gy = r0 + rr + ky - 1;
        if ((unsigned)gy < 128u) {
            int rb = (rr + ky) << 7;          // slot = rr+1+(ky-1)
#pragma unroll
            for (int kx = 0; kx < 3; ++kx) {
                int wx = w + kx - 1;
                if ((unsigned)wx < 128u)
                    acc += wp[ky * 3 + kx] * ip[rb + wx];
            }
        }
    }
    f3[(size_t)c * NF + p] = acc;
}

// ---------------------------------------------------------------------------
extern "C" void kernel_launch(void* const* d_in, const int* in_sizes, int n_in,
                              void* d_out, int out_size, void* d_ws, size_t ws_size,
                              hipStream_t stream) {
    const float* x      = (const float*)d_in[0];
    const float* ln1w   = (const float*)d_in[1];
    const float* ln1b   = (const float*)d_in[2];
    const float* qkv_w  = (const float*)d_in[3];
    const float* qkv_b  = (const float*)d_in[4];
    const float* qdw_w  = (const float*)d_in[5];
    const float* qdw_b  = (const float*)d_in[6];
    const float* temp   = (const float*)d_in[7];
    const float* prompt = (const float*)d_in[8];
    const float* proj_w = (const float*)d_in[9];
    const float* proj_b = (const float*)d_in[10];
    const float* ln2w   = (const float*)d_in[11];
    const float* ln2b   = (const float*)d_in[12];
    const float* dw1_w  = (const float*)d_in[13];
    const float* dw1_b  = (const float*)d_in[14];
    const float* pm_w   = (const float*)d_in[15];
    const float* pm_b   = (const float*)d_in[16];
    const float* dw2_w  = (const float*)d_in[17];
    const float* dw2_b  = (const float*)d_in[18];
    const float* po_w   = (const float*)d_in[19];
    const float* po_b   = (const float*)d_in[20];
    float* out = (float*)d_out;
    (void)in_sizes; (void)n_in;

    // Fixed minimal arena (~40.3 MB) — sized to fit a small d_ws.
    size_t off = 0;
    char* base = (char*)d_ws;
    auto alloc = [&](size_t bytes) -> char* {
        char* p = base + off;
        off = (off + bytes + 255) & ~(size_t)255;
        return p;
    };
    float* slotA = (float*)alloc((size_t)384 * HW * 4);   // q~k~ | v~/x2 (lo), f2 (hi)
    float* slotB = (float*)alloc((size_t)192 * HW * 4);   // q/k/v pre-dw | attnout | f1/f3
    float* G0p   = (float*)alloc((size_t)4 * 64 * 2304 * 4);
    float* Amat  = (float*)alloc((size_t)4 * 2304 * 4);
    float* invn  = (float*)alloc(384 * 4);
    float* muv   = (float*)alloc((size_t)HW * 4);
    float* rsv   = (float*)alloc((size_t)HW * 4);
    float* x2 = slotA;                         // 192 ch, reuses q~ region
    float* f2 = slotA + (size_t)192 * HW;      // 576 ch x NT, fits in slotA upper half
    float* f1 = slotB;                         // 576 ch x NT (10.03 MB <= 12.58 MB)
    float* f3 = slotB;                         // 576 ch x NF, overwrites dead f1

    // Deterministic initial state regardless of harness poison.
    hipMemsetAsync(d_ws, 0, off <= ws_size ? off : ws_size, stream);
    hipMemsetAsync(d_out, 0, (size_t)out_size * sizeof(float), stream);

    dim3 blk(256);
    for (int b = 0; b < NB; ++b) {
        const float* xb = x + (size_t)b * CDIM * HW;
        float* outb     = out + (size_t)b * CDIM * HW;

        // --- attention ---
        ln_stats1<<<dim3(64), blk, 0, stream>>>(xb, muv, rsv);
        // q
        gemm1<0, 0><<<dim3(64, 3), blk, 0, stream>>>(
            qkv_w, xb, HW, muv, rsv, ln1w, ln1b, qkv_b,
            nullptr, 0, slotB, HW, CDIM, CDIM);
        dwp<<<dim3(64, 192), blk, 0, stream>>>(slotB, qdw_w, qdw_b, prompt, slotA);
        // k
        gemm1<0, 0><<<dim3(64, 3), blk, 0, stream>>>(
            qkv_w + 192 * CDIM, xb, HW, muv, rsv, ln1w, ln1b, qkv_b + 192,
            nullptr, 0, slotB, HW, CDIM, CDIM);
        dwp<<<dim3(64, 192), blk, 0, stream>>>(slotB, qdw_w + 192 * 9, qdw_b + 192,
                                               prompt, slotA + (size_t)192 * HW);
        inv_norms1<<<dim3(384), blk, 0, stream>>>(slotA, invn);
        gram1<<<dim3(16, 4), blk, 0, stream>>>(slotA, G0p);
        softmax1<<<dim3(4), dim3(64), 0, stream>>>(G0p, invn, temp, Amat);
        // v  (q~k~ dead; v~ overwrites slotA lo)
        gemm1<0, 0><<<dim3(64, 3), blk, 0, stream>>>(
            qkv_w + 384 * CDIM, xb, HW, muv, rsv, ln1w, ln1b, qkv_b + 384,
            nullptr, 0, slotB, HW, CDIM, CDIM);
        dwp<<<dim3(64, 192), blk, 0, stream>>>(slotB, qdw_w + 384 * 9, qdw_b + 384,
                                               prompt, slotA);
        apply1<<<dim3(64, 4), blk, 0, stream>>>(slotA, Amat, slotB);
        // proj + residual -> x2 (slotA lo; v~ dead)
        gemm1<1, 2><<<dim3(64, 3), blk, 0, stream>>>(
            proj_w, slotB, HW, nullptr, nullptr, nullptr, nullptr, proj_b,
            xb, HW, x2, HW, CDIM, CDIM);

        // --- FFN, 4 row-tiles ---
        ln_stats1<<<dim3(64), blk, 0, stream>>>(x2, muv, rsv);
        for (int t = 0; t < 4; ++t) {
            int r0 = t * TROWS;
            dwln_tile<<<dim3(NT / 256, CH3), blk, 0, stream>>>(
                x2, muv, rsv, ln2w, ln2b, dw1_w, dw1_b, f1, r0);
            gemm1<1, 1><<<dim3(NT / 256, 9), blk, 0, stream>>>(
                pm_w, f1, NT, nullptr, nullptr, nullptr, nullptr, pm_b,
                nullptr, 0, f2, NT, CH3, CH3);
            dw2_tile<<<dim3(NF / 256, CH3), blk, 0, stream>>>(f2, dw2_w, dw2_b, f3, r0);
            gemm1<1, 2><<<dim3(NF / 256, 3), blk, 0, stream>>>(
                po_w, f3, NF, nullptr, nullptr, nullptr, nullptr, po_b,
                x2 + (size_t)r0 * 128, HW, outb + (size_t)r0 * 128, HW, CDIM, CH3);
        }
    }
}

// Round 7
// 4399.014 us; speedup vs baseline: 2.2205x; 2.2205x over previous
//
#include <hip/hip_runtime.h>

// Problem constants
#define HW     16384      // 128*128
#define NB     8
#define CDIM   192
#define CH3    576
#define NHEADS 4
#define CHH    48
#define TROWS  16           // FFN tile rows
#define TSLOT  18           // + halo
#define NT     (TSLOT*128)  // 2304
#define NF     (TROWS*128)  // 2048
#define NGRP   4            // batches per FFN group
#define LDA    40           // LDS k-stride (bf16 elems): 80B, 16B-mult, 2-way-free banks

typedef short  v8s  __attribute__((ext_vector_type(8)));
typedef float  v4f  __attribute__((ext_vector_type(4)));
typedef unsigned short u16x8 __attribute__((ext_vector_type(8)));

__device__ __forceinline__ float bf2f(unsigned short s) {
    return __uint_as_float(((unsigned)s) << 16);
}
__device__ __forceinline__ unsigned short f2bf(float f) {
    unsigned u = __float_as_uint(f);
    return (unsigned short)((u + 0x7fffu + ((u >> 16) & 1u)) >> 16);
}
__device__ __forceinline__ float gelu_f(float x) {
    return 0.5f * x * (1.0f + erff(x * 0.70710678118654752f));
}

// ---------------------------------------------------------------------------
// LayerNorm stats per pixel over 192 channels. grid (64, Z)
// ---------------------------------------------------------------------------
__global__ __launch_bounds__(256) void ln_stats(const float* __restrict__ x,
                                                float* __restrict__ mu,
                                                float* __restrict__ rstd) {
    int p = blockIdx.x * 256 + threadIdx.x;
    int z = blockIdx.y;
    const float* xp = x + (size_t)z * CDIM * HW;
    float s = 0.f, ss = 0.f;
    for (int c = 0; c < CDIM; ++c) {
        float v = xp[(size_t)c * HW + p];
        s += v; ss += v * v;
    }
    float m = s * (1.0f / CDIM);
    float var = ss * (1.0f / CDIM) - m * m;
    mu[z * HW + p] = m;
    rstd[z * HW + p] = 1.0f / sqrtf(var + 1e-5f);
}

// ---------------------------------------------------------------------------
// MFMA bf16 GEMM: out[m,n] = sum_k W[m,k] * X[k,n]  (fp32 acc/epilogue)
// Block: 256 thr = 4 waves (2x2), tile M=64 x N=128, K-step 32.
// B_MODE 0: X = layernorm(fp32 Bin) cast bf16 at stage; 1: bf16 buffer.
// EPI 0: +bias -> bf16; 1: +bias,gelu -> bf16; 2: +bias,+res(fp32) -> fp32.
// grid (N/128, M/64, Z)
// ---------------------------------------------------------------------------
template <int B_MODE, int EPI>
__global__ __launch_bounds__(256) void gemm_mfma(
    const float* __restrict__ Aw,
    const void* __restrict__ Bin, int b_cs, long b_zs,
    const float* __restrict__ mu, const float* __restrict__ rstd,
    const float* __restrict__ lnw, const float* __restrict__ lnb,
    const float* __restrict__ bias,
    const float* __restrict__ res, int r_cs, long r_zs,
    void* __restrict__ outp, int o_cs, long o_zs,
    int M, int K) {
    __shared__ unsigned short Albs[64 * LDA];
    __shared__ unsigned short Blbs[128 * LDA];

    const int t  = threadIdx.x;
    const int n0 = blockIdx.x * 128;
    const int m0 = blockIdx.y * 64;
    const int z  = blockIdx.z;

    const int wid = t >> 6, lane = t & 63;
    const int lm = lane & 15, quad = lane >> 4;
    const int wm = (wid & 1) * 32, wn = (wid >> 1) * 64;

    v4f acc[2][4];
#pragma unroll
    for (int mi = 0; mi < 2; ++mi)
#pragma unroll
        for (int ni = 0; ni < 4; ++ni) acc[mi][ni] = (v4f)0.0f;

    // staging coords
    const int am = t >> 2, kc = (t & 3) << 3;       // A: 64 m x 4 k-chunks of 8
    const int bk = t >> 3, nc = (t & 7) << 4;       // B: 32 k x 8 n-chunks of 16

    for (int k0 = 0; k0 < K; k0 += 32) {
        if (k0) __syncthreads();
        // --- stage A (64 x 32), fp32 -> bf16, layout [m][k] ---
        {
            const float* wp = Aw + (size_t)(m0 + am) * K + k0 + kc;
            float4 w0 = *(const float4*)wp;
            float4 w1 = *(const float4*)(wp + 4);
            u16x8 u;
            u[0] = f2bf(w0.x); u[1] = f2bf(w0.y); u[2] = f2bf(w0.z); u[3] = f2bf(w0.w);
            u[4] = f2bf(w1.x); u[5] = f2bf(w1.y); u[6] = f2bf(w1.z); u[7] = f2bf(w1.w);
            *(u16x8*)&Albs[am * LDA + kc] = u;
        }
        // --- stage B (32 k x 128 n) transposed to [n][k] ---
        if (B_MODE == 1) {
            const unsigned short* bp = (const unsigned short*)Bin + (size_t)z * b_zs +
                                       (size_t)(k0 + bk) * b_cs + n0 + nc;
            u16x8 u0 = *(const u16x8*)bp;
            u16x8 u1 = *(const u16x8*)(bp + 8);
#pragma unroll
            for (int i = 0; i < 8; ++i) {
                Blbs[(nc + i) * LDA + bk]     = u0[i];
                Blbs[(nc + 8 + i) * LDA + bk] = u1[i];
            }
        } else {
            const float* xp = (const float*)Bin + (size_t)z * b_zs +
                              (size_t)(k0 + bk) * b_cs + n0 + nc;
            const float* mp = mu + n0 + nc;
            const float* rp = rstd + n0 + nc;
            float lw = lnw[k0 + bk], lb = lnb[k0 + bk];
#pragma unroll
            for (int q = 0; q < 4; ++q) {
                float4 xv = *(const float4*)(xp + 4 * q);
                float4 mv = *(const float4*)(mp + 4 * q);
                float4 rv = *(const float4*)(rp + 4 * q);
                Blbs[(nc + 4 * q + 0) * LDA + bk] = f2bf((xv.x - mv.x) * rv.x * lw + lb);
                Blbs[(nc + 4 * q + 1) * LDA + bk] = f2bf((xv.y - mv.y) * rv.y * lw + lb);
                Blbs[(nc + 4 * q + 2) * LDA + bk] = f2bf((xv.z - mv.z) * rv.z * lw + lb);
                Blbs[(nc + 4 * q + 3) * LDA + bk] = f2bf((xv.w - mv.w) * rv.w * lw + lb);
            }
        }
        __syncthreads();
        // --- 2x4 MFMA 16x16x32 ---
        v8s a[2], b[4];
#pragma unroll
        for (int mi = 0; mi < 2; ++mi)
            a[mi] = *(const v8s*)&Albs[(wm + mi * 16 + lm) * LDA + quad * 8];
#pragma unroll
        for (int ni = 0; ni < 4; ++ni)
            b[ni] = *(const v8s*)&Blbs[(wn + ni * 16 + lm) * LDA + quad * 8];
#pragma unroll
        for (int mi = 0; mi < 2; ++mi)
#pragma unroll
            for (int ni = 0; ni < 4; ++ni)
                acc[mi][ni] = __builtin_amdgcn_mfma_f32_16x16x32_bf16(
                    a[mi], b[ni], acc[mi][ni], 0, 0, 0);
    }

    // --- epilogue: D row = quad*4+r, col = lm ---
#pragma unroll
    for (int mi = 0; mi < 2; ++mi)
#pragma unroll
        for (int ni = 0; ni < 4; ++ni)
#pragma unroll
            for (int r = 0; r < 4; ++r) {
                int gm = m0 + wm + mi * 16 + quad * 4 + r;
                int gn = n0 + wn + ni * 16 + lm;
                float v = acc[mi][ni][r] + bias[gm];
                if (EPI == 1) v = gelu_f(v);
                if (EPI == 2) {
                    size_t ri = (size_t)z * r_zs + (size_t)gm * r_cs + gn;
                    size_t oi = (size_t)z * o_zs + (size_t)gm * o_cs + gn;
                    ((float*)outp)[oi] = v + res[ri];
                } else {
                    size_t oi = (size_t)z * o_zs + (size_t)gm * o_cs + gn;
                    ((unsigned short*)outp)[oi] = f2bf(v);
                }
            }
}

// ---------------------------------------------------------------------------
// Depthwise 3x3 (pad=1) + bias + prompt[c%192] on 576-ch bf16. grid (64, 576)
// ---------------------------------------------------------------------------
__global__ __launch_bounds__(256) void dwp(const unsigned short* __restrict__ in,
                                           const float* __restrict__ w9,
                                           const float* __restrict__ b1,
                                           const float* __restrict__ prompt,
                                           unsigned short* __restrict__ out) {
    int p = blockIdx.x * 256 + threadIdx.x;
    int c = blockIdx.y;
    int h = p >> 7, w = p & 127;
    const unsigned short* ip = in + (size_t)c * HW;
    const float* wp = w9 + c * 9;
    float acc = b1[c] + prompt[c % CDIM];
#pragma unroll
    for (int ky = 0; ky < 3; ++ky) {
        int hy = h + ky - 1;
        if ((unsigned)hy < 128u) {
            int rb = hy << 7;
#pragma unroll
            for (int kx = 0; kx < 3; ++kx) {
                int wx = w + kx - 1;
                if ((unsigned)wx < 128u)
                    acc += wp[ky * 3 + kx] * bf2f(ip[rb + wx]);
            }
        }
    }
    out[(size_t)c * HW + p] = f2bf(acc);
}

// ---------------------------------------------------------------------------
// 1/max(L2norm,1e-12) per q,k channel (0..383). grid 384
// ---------------------------------------------------------------------------
__global__ __launch_bounds__(256) void inv_norms1(const unsigned short* __restrict__ qk,
                                                  float* __restrict__ invn) {
    int ch = blockIdx.x;
    const unsigned short* p = qk + (size_t)ch * HW;
    float ss = 0.f;
    for (int i = threadIdx.x; i < HW; i += 256) { float v = bf2f(p[i]); ss += v * v; }
    __shared__ float r[256];
    r[threadIdx.x] = ss;
    __syncthreads();
    for (int off = 128; off; off >>= 1) {
        if (threadIdx.x < (unsigned)off) r[threadIdx.x] += r[threadIdx.x + off];
        __syncthreads();
    }
    if (threadIdx.x == 0) invn[ch] = 1.0f / fmaxf(sqrtf(r[0]), 1e-12f);
}

// ---------------------------------------------------------------------------
// Gram partials: G0p[h*32 + sl*4 + ns][c][d]. grid (8 slices, 4 heads)
// ---------------------------------------------------------------------------
__global__ __launch_bounds__(256) void gram1(const unsigned short* __restrict__ qk,
                                             float* __restrict__ G0p) {
    int sl = blockIdx.x, h = blockIdx.y;
    const int tid = threadIdx.x;
    const int ns = tid >> 6;
    const int lane = tid & 63;
    const int ci = lane >> 3;
    const int di = lane & 7;

    __shared__ float qs[48][68];
    __shared__ float ks[48][68];

    float acc[6][6];
#pragma unroll
    for (int i = 0; i < 6; ++i)
#pragma unroll
        for (int j = 0; j < 6; ++j) acc[i][j] = 0.f;

    const size_t qbase = (size_t)(h * CHH) * HW;
    const size_t kbase = (size_t)(192 + h * CHH) * HW;
    const int nstart = sl << 11;     // 2048 per slice

    for (int t = 0; t < 2048; t += 64) {
        __syncthreads();
        for (int sidx = tid; sidx < 768; sidx += 256) {
            int which = sidx >= 384;
            int r  = (sidx & 383) >> 3;
            int c8 = (sidx & 7) << 3;
            size_t src = (which ? kbase : qbase) + (size_t)r * HW + nstart + t + c8;
            u16x8 u = *(const u16x8*)(qk + src);
            float* dst = which ? &ks[r][c8] : &qs[r][c8];
#pragma unroll
            for (int j = 0; j < 8; ++j) dst[j] = bf2f(u[j]);
        }
        __syncthreads();
#pragma unroll
        for (int q4 = 0; q4 < 4; ++q4) {
            int n = (ns << 4) + (q4 << 2);
            float4 qv[6], kv[6];
#pragma unroll
            for (int i = 0; i < 6; ++i) qv[i] = *(const float4*)&qs[ci * 6 + i][n];
#pragma unroll
            for (int j = 0; j < 6; ++j) kv[j] = *(const float4*)&ks[di * 6 + j][n];
#pragma unroll
            for (int i = 0; i < 6; ++i)
#pragma unroll
                for (int j = 0; j < 6; ++j) {
                    acc[i][j] = fmaf(qv[i].x, kv[j].x, acc[i][j]);
                    acc[i][j] = fmaf(qv[i].y, kv[j].y, acc[i][j]);
                    acc[i][j] = fmaf(qv[i].z, kv[j].z, acc[i][j]);
                    acc[i][j] = fmaf(qv[i].w, kv[j].w, acc[i][j]);
                }
        }
    }
    float* gp = G0p + (size_t)(h * 32 + sl * 4 + ns) * 2304;
#pragma unroll
    for (int i = 0; i < 6; ++i)
#pragma unroll
        for (int j = 0; j < 6; ++j)
            gp[(ci * 6 + i) * 48 + di * 6 + j] = acc[i][j];
}

// ---------------------------------------------------------------------------
// logits = T*G*invq*invk; softmax over d. grid 4 x 64 thr
// ---------------------------------------------------------------------------
__global__ __launch_bounds__(64) void softmax1(const float* __restrict__ G0p,
                                               const float* __restrict__ invn,
                                               const float* __restrict__ temp,
                                               float* __restrict__ Amat) {
    int h = blockIdx.x;
    int c = threadIdx.x;
    __shared__ float invk_s[48];
    if (c < 48) invk_s[c] = invn[192 + h * CHH + c];
    __syncthreads();
    if (c >= 48) return;
    float T = temp[h];
    float invq = invn[h * CHH + c];
    const float* gp = G0p + (size_t)h * 32 * 2304 + c * 48;
    float lg[48];
    float mx = -1e30f;
    for (int d = 0; d < 48; ++d) {
        float g = 0.f;
        for (int s = 0; s < 32; ++s) g += gp[s * 2304 + d];
        float l = T * g * invq * invk_s[d];
        lg[d] = l;
        mx = fmaxf(mx, l);
    }
    float sum = 0.f;
    for (int d = 0; d < 48; ++d) { float e = expf(lg[d] - mx); lg[d] = e; sum += e; }
    float inv = 1.0f / sum;
    float* ap = Amat + (size_t)h * 2304 + c * 48;
    for (int d = 0; d < 48; ++d) ap[d] = lg[d] * inv;
}

// ---------------------------------------------------------------------------
// attnout[c,n] = sum_d A[c,d]*v~[d,n] per head (bf16 in/out). grid (64, 4)
// ---------------------------------------------------------------------------
__global__ __launch_bounds__(256) void apply1(const unsigned short* __restrict__ qkvT,
                                              const float* __restrict__ Amat,
                                              unsigned short* __restrict__ attnout) {
    int n = blockIdx.x * 256 + threadIdx.x;
    int h = blockIdx.y;
    __shared__ float As[2304];
    for (int i = threadIdx.x; i < 2304; i += 256) As[i] = Amat[(size_t)h * 2304 + i];
    __syncthreads();
    const unsigned short* vp = qkvT + (size_t)(384 + h * CHH) * HW + n;
    float acc[48];
#pragma unroll
    for (int c = 0; c < 48; ++c) acc[c] = 0.f;
    for (int d = 0; d < 48; ++d) {
        float v = bf2f(vp[(size_t)d * HW]);
#pragma unroll
        for (int c = 0; c < 48; ++c) acc[c] = fmaf(As[c * 48 + d], v, acc[c]);
    }
    unsigned short* op = attnout + (size_t)(h * CHH) * HW + n;
#pragma unroll
    for (int c = 0; c < 48; ++c) op[(size_t)c * HW] = f2bf(acc[c]);
}

// ---------------------------------------------------------------------------
// FFN grouped 3x3 (192->576) + LN fused, row-tile +halo, z-batched.
// grid (NT/256, 576, NGRP). Junk (finite) for invalid global rows.
// ---------------------------------------------------------------------------
__global__ __launch_bounds__(256) void dwln_tile(const float* __restrict__ x2,
                                                 const float* __restrict__ mu,
                                                 const float* __restrict__ rstd,
                                                 const float* __restrict__ lnw,
                                                 const float* __restrict__ lnb,
                                                 const float* __restrict__ w9,
                                                 const float* __restrict__ b1,
                                                 unsigned short* __restrict__ f1, int r0) {
    int p = blockIdx.x * 256 + threadIdx.x;   // 0..NT-1
    int c = blockIdx.y, z = blockIdx.z;
    int s = p >> 7, w = p & 127;
    int gr = r0 - 1 + s;
    int g = c / 3;
    const float* ip = x2 + (size_t)z * CDIM * HW + (size_t)g * HW;
    const float* mp = mu + (size_t)z * HW;
    const float* rp = rstd + (size_t)z * HW;
    float lw = lnw[g], lb = lnb[g];
    const float* wp = w9 + c * 9;
    float acc = b1[c];
#pragma unroll
    for (int ky = 0; ky < 3; ++ky) {
        int hy = gr + ky - 1;
        if ((unsigned)hy < 128u) {
            int rb = hy << 7;
#pragma unroll
            for (int kx = 0; kx < 3; ++kx) {
                int wx = w + kx - 1;
                if ((unsigned)wx < 128u) {
                    int idx = rb + wx;
                    float v = (ip[idx] - mp[idx]) * rp[idx] * lw + lb;
                    acc += wp[ky * 3 + kx] * v;
                }
            }
        }
    }
    f1[(size_t)z * CH3 * NT + (size_t)c * NT + p] = f2bf(acc);
}

// ---------------------------------------------------------------------------
// FFN depthwise 3x3 on f2 tile -> f3, z-batched. grid (NF/256, 576, NGRP)
// ---------------------------------------------------------------------------
__global__ __launch_bounds__(256) void dw2_tile(const unsigned short* __restrict__ f2,
                                                const float* __restrict__ w9,
                                                const float* __restrict__ b1,
                                                unsigned short* __restrict__ f3, int r0) {
    int p = blockIdx.x * 256 + threadIdx.x;   // 0..NF-1
    int c = blockIdx.y, z = blockIdx.z;
    int rr = p >> 7, w = p & 127;
    const unsigned short* ip = f2 + (size_t)z * CH3 * NT + (size_t)c * NT;
    const float* wp = w9 + c * 9;
    float acc = b1[c];
#pragma unroll
    for (int ky = 0; ky < 3; ++ky) {
        int gy = r0 + rr + ky - 1;
        if ((unsigned)gy < 128u) {
            int rb = (rr + ky) << 7;
#pragma unroll
            for (int kx = 0; kx < 3; ++kx) {
                int wx = w + kx - 1;
                if ((unsigned)wx < 128u)
                    acc += wp[ky * 3 + kx] * bf2f(ip[rb + wx]);
            }
        }
    }
    f3[(size_t)z * CH3 * NF + (size_t)c * NF + p] = f2bf(acc);
}

// ---------------------------------------------------------------------------
extern "C" void kernel_launch(void* const* d_in, const int* in_sizes, int n_in,
                              void* d_out, int out_size, void* d_ws, size_t ws_size,
                              hipStream_t stream) {
    const float* x      = (const float*)d_in[0];
    const float* ln1w   = (const float*)d_in[1];
    const float* ln1b   = (const float*)d_in[2];
    const float* qkv_w  = (const float*)d_in[3];
    const float* qkv_b  = (const float*)d_in[4];
    const float* qdw_w  = (const float*)d_in[5];
    const float* qdw_b  = (const float*)d_in[6];
    const float* temp   = (const float*)d_in[7];
    const float* prompt = (const float*)d_in[8];
    const float* proj_w = (const float*)d_in[9];
    const float* proj_b = (const float*)d_in[10];
    const float* ln2w   = (const float*)d_in[11];
    const float* ln2b   = (const float*)d_in[12];
    const float* dw1_w  = (const float*)d_in[13];
    const float* dw1_b  = (const float*)d_in[14];
    const float* pm_w   = (const float*)d_in[15];
    const float* pm_b   = (const float*)d_in[16];
    const float* dw2_w  = (const float*)d_in[17];
    const float* dw2_b  = (const float*)d_in[18];
    const float* po_w   = (const float*)d_in[19];
    const float* po_b   = (const float*)d_in[20];
    float* out = (float*)d_out;   // x2 lives here between proj and po
    (void)in_sizes; (void)n_in; (void)out_size; (void)ws_size;

    // Arena (~39.5 MB, < proven-safe 41.3 MB)
    size_t off = 0;
    char* base = (char*)d_ws;
    auto alloc = [&](size_t bytes) -> char* {
        char* p = base + off;
        off = (off + bytes + 255) & ~(size_t)255;
        return p;
    };
    unsigned short* regionA = (unsigned short*)alloc((size_t)CH3 * HW * 2); // preQKV | attnout | f1,f3
    unsigned short* regionB = (unsigned short*)alloc((size_t)CH3 * HW * 2); // qkvT | f2
    float* G0p  = (float*)alloc((size_t)4 * 32 * 2304 * 4);
    float* Amat = (float*)alloc((size_t)4 * 2304 * 4);
    float* invn = (float*)alloc(384 * 4);
    float* muv  = (float*)alloc((size_t)NGRP * HW * 4);
    float* rsv  = (float*)alloc((size_t)NGRP * HW * 4);

    unsigned short* preQKV  = regionA;
    unsigned short* attnout = regionA;
    unsigned short* f1      = regionA;
    unsigned short* f3      = regionA;   // aliases f1 (f1 dead when dw2 runs)
    unsigned short* qkvT    = regionB;
    unsigned short* f2      = regionB;

    dim3 blk(256);

    // ---------------- phase 1+2: attention, per batch ----------------
    for (int b = 0; b < NB; ++b) {
        const float* xb = x + (size_t)b * CDIM * HW;
        float* x2b      = out + (size_t)b * CDIM * HW;

        ln_stats<<<dim3(64, 1), blk, 0, stream>>>(xb, muv, rsv);

        // qkv 1x1 (LN-fused) -> preQKV bf16   [grid 128x9 = 1152 blocks]
        gemm_mfma<0, 0><<<dim3(HW / 128, CH3 / 64, 1), blk, 0, stream>>>(
            qkv_w, xb, HW, 0, muv, rsv, ln1w, ln1b, qkv_b,
            nullptr, 0, 0, preQKV, HW, 0, CH3, CDIM);

        // depthwise 3x3 + prompt -> qkvT bf16
        dwp<<<dim3(64, CH3), blk, 0, stream>>>(preQKV, qdw_w, qdw_b, prompt, qkvT);

        inv_norms1<<<dim3(384), blk, 0, stream>>>(qkvT, invn);
        gram1<<<dim3(8, 4), blk, 0, stream>>>(qkvT, G0p);
        softmax1<<<dim3(4), dim3(64), 0, stream>>>(G0p, invn, temp, Amat);
        apply1<<<dim3(64, 4), blk, 0, stream>>>(qkvT, Amat, attnout);

        // proj 1x1 + residual(x) -> x2 (fp32, in d_out)   [grid 128x3]
        gemm_mfma<1, 2><<<dim3(HW / 128, CDIM / 64, 1), blk, 0, stream>>>(
            proj_w, attnout, HW, 0, nullptr, nullptr, nullptr, nullptr, proj_b,
            xb, HW, 0, x2b, HW, 0, CDIM, CDIM);
    }

    // ---------------- phase 3+4: FFN, groups of NGRP batches ----------------
    for (int g0 = 0; g0 < NB; g0 += NGRP) {
        float* x2g = out + (size_t)g0 * CDIM * HW;

        ln_stats<<<dim3(64, NGRP), blk, 0, stream>>>(x2g, muv, rsv);

        for (int t = 0; t < 128 / TROWS; ++t) {
            int r0 = t * TROWS;
            dwln_tile<<<dim3(NT / 256, CH3, NGRP), blk, 0, stream>>>(
                x2g, muv, rsv, ln2w, ln2b, dw1_w, dw1_b, f1, r0);
            // pm 576->576 + gelu -> f2 bf16   [grid 18x9x4 = 648 blocks]
            gemm_mfma<1, 1><<<dim3(NT / 128, CH3 / 64, NGRP), blk, 0, stream>>>(
                pm_w, f1, NT, (long)CH3 * NT, nullptr, nullptr, nullptr, nullptr, pm_b,
                nullptr, 0, 0, f2, NT, (long)CH3 * NT, CH3, CH3);
            dw2_tile<<<dim3(NF / 256, CH3, NGRP), blk, 0, stream>>>(
                f2, dw2_w, dw2_b, f3, r0);
            // po 576->192 + residual(x2 rows) -> out rows  [grid 16x3x4 = 192]
            gemm_mfma<1, 2><<<dim3(NF / 128, CDIM / 64, NGRP), blk, 0, stream>>>(
                po_w, f3, NF, (long)CH3 * NF, nullptr, nullptr, nullptr, nullptr, po_b,
                x2g + (size_t)r0 * 128, HW, (long)CDIM * HW,
                x2g + (size_t)r0 * 128, HW, (long)CDIM * HW, CDIM, CH3);
        }
    }
}